// Round 21
// baseline (67.713 us; speedup 1.0000x reference)
//
#include <hip/hip_runtime.h>

// NNConv x3 + MLP head, 5 dispatches.
// W_e = a0*A0 + a1*A1 + B (affine in 2 edge attrs) =>
//   aggr_n = [s0;s1;s2;s3] @ [A0;A1;B;R],  s0=sum a0*h_src, s1=sum a1*h_src,
//   s2=sum w*h_src (w=1), s3=h_self.
// Padded CSR (CAP=32), reg-clamped pads. R21: fused kernels are GRID-STRIDE
// persistent (512 blocks = 2/CU, loop over 625 32-node tiles) -> weight
// staging paid once per BLOCK not per tile; waves stay resident between tiles.
// Scatter: 293 blocks (2 edges/thread) so all CUs participate.
// Kernels: zero(cnt) | scatter | conv1 | fused2 | fused3+head.

#define CAP 32

typedef float f32x4 __attribute__((ext_vector_type(4)));
typedef short s16x8 __attribute__((ext_vector_type(8)));

__device__ __forceinline__ unsigned short f2bf(float x) {
    unsigned u = __float_as_uint(x);
    unsigned r = u + 0x7FFFu + ((u >> 16) & 1u);
    return (unsigned short)(r >> 16);
}
__device__ __forceinline__ float bf2f(unsigned short h) {
    return __uint_as_float(((unsigned)h) << 16);
}

__global__ __launch_bounds__(256) void zero_kernel(int* p, int n) {
    int i = blockIdx.x * 256 + threadIdx.x;
    if (i < n) p[i] = 0;
}

__global__ __launch_bounds__(256) void scatter_kernel(
    const int* __restrict__ src, const int* __restrict__ dst,
    const float* __restrict__ ea, int* __restrict__ cnt,
    int4* __restrict__ edges, int E) {
    int tid = blockIdx.x * 256 + threadIdx.x;
    int T = gridDim.x * 256;
#pragma unroll 2
    for (int k = 0; k < 2; ++k) {
        int e = tid + k * T;
        if (e < E) {
            int d = dst[e];
            int p = atomicAdd(&cnt[d], 1);
            if (p < CAP) {
                float2 a = ((const float2*)ea)[e];
                int4 ed;
                ed.x = __float_as_int(1.0f);
                ed.y = __float_as_int(a.x);
                ed.z = __float_as_int(a.y);
                ed.w = src[e] * 32;
                edges[((size_t)d << 5) + p] = ed;
            }
        }
    }
}

// conv1: in=2, out=32. 8 nodes/block (half-wave each). Rec-clamped pads;
// 8-wide batches via shfl broadcasts.
__global__ __launch_bounds__(256) void conv1_kernel(
    const float* __restrict__ x, const int* __restrict__ cnt,
    const int4* __restrict__ edges, const float* __restrict__ nnW,
    const float* __restrict__ nnb, const float* __restrict__ root,
    const float* __restrict__ bias, float* __restrict__ hout, int N) {
    int tid = threadIdx.x;
    int g = tid >> 5, lane = tid & 31;
    int n = blockIdx.x * 8 + g;
    if (n >= N) return;
    int deg = cnt[n];
    deg = (deg < CAP) ? deg : CAP;
    int deg8 = (deg + 7) & ~7;
    const int4* ep = &edges[(size_t)n << 5];
    int4 rec = {0, 0, 0, 0};
    if (lane < deg) rec = ep[lane];
    float p0 = 0, p1 = 0, q0 = 0, q1 = 0, r0 = 0, r1 = 0;
    for (int p = 0; p < deg8; p += 8) {
        float2 xv[8];
        float a0[8], a1[8], ww[8];
#pragma unroll
        for (int j = 0; j < 8; ++j) {
            int off = __shfl(rec.w, p + j, 32);
            a0[j] = __int_as_float(__shfl(rec.y, p + j, 32));
            a1[j] = __int_as_float(__shfl(rec.z, p + j, 32));
            ww[j] = __int_as_float(__shfl(rec.x, p + j, 32));
            xv[j] = ((const float2*)x)[off >> 5];
        }
#pragma unroll
        for (int j = 0; j < 8; ++j) {
            p0 = fmaf(a0[j], xv[j].x, p0);
            p1 = fmaf(a0[j], xv[j].y, p1);
            q0 = fmaf(a1[j], xv[j].x, q0);
            q1 = fmaf(a1[j], xv[j].y, q1);
            r0 = fmaf(ww[j], xv[j].x, r0);
            r1 = fmaf(ww[j], xv[j].y, r1);
        }
    }
    float acc = bias[lane];
    acc = fmaf(p0, nnW[lane * 2], acc);
    acc = fmaf(p1, nnW[(32 + lane) * 2], acc);
    acc = fmaf(q0, nnW[lane * 2 + 1], acc);
    acc = fmaf(q1, nnW[(32 + lane) * 2 + 1], acc);
    acc = fmaf(r0, nnb[lane], acc);
    acc = fmaf(r1, nnb[32 + lane], acc);
    float2 xn = ((const float2*)x)[n];
    acc = fmaf(xn.x, root[lane], acc);
    acc = fmaf(xn.y, root[32 + lane], acc);
    hout[n * 32 + lane] = fmaxf(acc, 0.f);
}

// Stage the 4x[32x32] weight stack transposed into LDS as bf16 hi/lo:
// Whi[kc][o][k]. kc: 0=A0, 1=A1, 2=B(nnb), 3=R(root).
template <int BS>
__device__ __forceinline__ void stage_weights(
    const float* __restrict__ nnW, const float* __restrict__ nnb,
    const float* __restrict__ root, unsigned short (*Whi)[32][32],
    unsigned short (*Wlo)[32][32], int t) {
    for (int idx = t; idx < 4096; idx += BS) {
        int kc = idx >> 10, r = idx & 1023, k = r >> 5, o = r & 31;
        float v = (kc == 0)   ? nnW[(k * 32 + o) * 2]
                  : (kc == 1) ? nnW[(k * 32 + o) * 2 + 1]
                  : (kc == 2) ? nnb[k * 32 + o]
                              : root[k * 32 + o];
        unsigned short hb = f2bf(v);
        Whi[kc][o][k] = hb;
        Wlo[kc][o][k] = f2bf(v - bf2f(hb));
    }
}

#define MFMA_BF16 __builtin_amdgcn_mfma_f32_16x16x32_bf16

// Gather: 32 half-wave groups (1024-thr block), ONE node each, single pass.
// Rec-clamped pads; 8-wide batches; 8 independent h-row loads in flight.
__device__ __forceinline__ void gather_to_lds(
    const float* __restrict__ h, const int* __restrict__ cnt,
    const int4* __restrict__ edges, float (*Sl)[132], int base, int t, int N) {
    int g = t >> 5, lane = t & 31;  // g in [0,32)
    int n = base + g;
    float s0 = 0, s1 = 0, s2 = 0, s3 = 0;
    if (n < N) {
        int deg = cnt[n];
        deg = (deg < CAP) ? deg : CAP;
        int deg8 = (deg + 7) & ~7;
        const int4* ep = &edges[(size_t)n << 5];
        int4 rec = {0, 0, 0, 0};
        if (lane < deg) rec = ep[lane];
        s3 = h[n * 32 + lane];
        for (int p = 0; p < deg8; p += 8) {
            float hv[8], a0[8], a1[8], ww[8];
#pragma unroll
            for (int j = 0; j < 8; ++j) {
                int off = __shfl(rec.w, p + j, 32);
                a0[j] = __int_as_float(__shfl(rec.y, p + j, 32));
                a1[j] = __int_as_float(__shfl(rec.z, p + j, 32));
                ww[j] = __int_as_float(__shfl(rec.x, p + j, 32));
                hv[j] = h[off + lane];
            }
#pragma unroll
            for (int j = 0; j < 8; ++j) {
                s0 = fmaf(a0[j], hv[j], s0);
                s1 = fmaf(a1[j], hv[j], s1);
                s2 = fmaf(ww[j], hv[j], s2);
            }
        }
    }
    Sl[g][lane] = s0;
    Sl[g][32 + lane] = s1;
    Sl[g][64 + lane] = s2;
    Sl[g][96 + lane] = s3;
}

// MFMA tile: acc = S-tile @ [A0;A1;B;R]. A-frag row=c, k=q*8+e;
// C/D row=q*4+rr, col=c (m89-verified, R8-validated end-to-end).
__device__ __forceinline__ void tile_mfma(
    const float (*Sl)[132], const unsigned short (*Whi)[32][32],
    const unsigned short (*Wlo)[32][32], int q, int c, f32x4* acc0, f32x4* acc1) {
#pragma unroll
    for (int kc = 0; kc < 4; ++kc) {
        const float* sp = &Sl[c][kc * 32 + q * 8];
        s16x8 ah, al;
#pragma unroll
        for (int e = 0; e < 8; ++e) {
            float v = sp[e];
            unsigned short hb = f2bf(v);
            ah[e] = (short)hb;
            al[e] = (short)f2bf(v - bf2f(hb));
        }
        s16x8 bh0 = *reinterpret_cast<const s16x8*>(&Whi[kc][c][q * 8]);
        s16x8 bl0 = *reinterpret_cast<const s16x8*>(&Wlo[kc][c][q * 8]);
        s16x8 bh1 = *reinterpret_cast<const s16x8*>(&Whi[kc][16 + c][q * 8]);
        s16x8 bl1 = *reinterpret_cast<const s16x8*>(&Wlo[kc][16 + c][q * 8]);
        *acc0 = MFMA_BF16(ah, bh0, *acc0, 0, 0, 0);
        *acc0 = MFMA_BF16(al, bh0, *acc0, 0, 0, 0);
        *acc0 = MFMA_BF16(ah, bl0, *acc0, 0, 0, 0);
        *acc1 = MFMA_BF16(ah, bh1, *acc1, 0, 0, 0);
        *acc1 = MFMA_BF16(al, bh1, *acc1, 0, 0, 0);
        *acc1 = MFMA_BF16(ah, bl1, *acc1, 0, 0, 0);
    }
}

// fused2: grid-stride over 32-node tiles. 1024 thr; staging once per block.
__global__ __launch_bounds__(1024) void fused2_kernel(
    const float* __restrict__ h, const int* __restrict__ cnt,
    const int4* __restrict__ edges, const float* __restrict__ nnW,
    const float* __restrict__ nnb, const float* __restrict__ root,
    const float* __restrict__ bias, float* __restrict__ hout, int N) {
    __shared__ unsigned short Whi[4][32][32], Wlo[4][32][32];
    __shared__ float Sl[32][132];
    int t = threadIdx.x;
    stage_weights<1024>(nnW, nnb, root, Whi, Wlo, t);
    int ntiles = (N + 31) >> 5;
    for (int tb = blockIdx.x; tb < ntiles; tb += gridDim.x) {
        int base = tb * 32;
        gather_to_lds(h, cnt, edges, Sl, base, t, N);
        __syncthreads();
        if (t < 128) {
            int tile = t >> 6;
            int l = t & 63;
            int q = l >> 4, c = l & 15;
            f32x4 acc0 = {0.f, 0.f, 0.f, 0.f}, acc1 = {0.f, 0.f, 0.f, 0.f};
            tile_mfma(&Sl[tile * 16], Whi, Wlo, q, c, &acc0, &acc1);
            float bb0 = bias[c], bb1 = bias[16 + c];
#pragma unroll
            for (int rr = 0; rr < 4; ++rr) {
                int n = base + tile * 16 + q * 4 + rr;
                if (n < N) {
                    hout[(size_t)n * 32 + c] = fmaxf(acc0[rr] + bb0, 0.f);
                    hout[(size_t)n * 32 + 16 + c] = fmaxf(acc1[rr] + bb1, 0.f);
                }
            }
        }
        __syncthreads();  // Sl reuse barrier for next tile
    }
}

// fused3: grid-stride tiles; conv3 + fused head -> out[N].
__global__ __launch_bounds__(1024) void fused3_kernel(
    const float* __restrict__ h, const int* __restrict__ cnt,
    const int4* __restrict__ edges, const float* __restrict__ nnW,
    const float* __restrict__ nnb, const float* __restrict__ root,
    const float* __restrict__ bias, const float* __restrict__ fc1W,
    const float* __restrict__ fc1b, const float* __restrict__ fc2W,
    const float* __restrict__ fc2b, float* __restrict__ out, int N) {
    __shared__ unsigned short Whi[4][32][32], Wlo[4][32][32];
    __shared__ float Sl[32][132];
    __shared__ unsigned short Th[32][32], Tl[32][32];
    int t = threadIdx.x;
    stage_weights<1024>(nnW, nnb, root, Whi, Wlo, t);
    int tile = t >> 6;
    int l = t & 63;
    int q = l >> 4, c = l & 15;
    // fc1 B-frags are block-invariant: load once.
    s16x8 fh[2], fl[2];
#pragma unroll
    for (int nc = 0; nc < 2; ++nc)
#pragma unroll
        for (int e = 0; e < 8; ++e) {
            float v = fc1W[(nc * 16 + c) * 32 + q * 8 + e];
            unsigned short hb = f2bf(v);
            fh[nc][e] = (short)hb;
            fl[nc][e] = (short)f2bf(v - bf2f(hb));
        }
    int ntiles = (N + 31) >> 5;
    for (int tb = blockIdx.x; tb < ntiles; tb += gridDim.x) {
        int base = tb * 32;
        gather_to_lds(h, cnt, edges, Sl, base, t, N);
        __syncthreads();
        if (t < 128) {
            f32x4 acc0 = {0.f, 0.f, 0.f, 0.f}, acc1 = {0.f, 0.f, 0.f, 0.f};
            tile_mfma(&Sl[tile * 16], Whi, Wlo, q, c, &acc0, &acc1);
            float bb0 = bias[c], bb1 = bias[16 + c];
#pragma unroll
            for (int rr = 0; rr < 4; ++rr) {
                int row = tile * 16 + q * 4 + rr;
                float v0 = fmaxf(acc0[rr] + bb0, 0.f);
                float v1 = fmaxf(acc1[rr] + bb1, 0.f);
                unsigned short hb;
                hb = f2bf(v0); Th[row][c] = hb;      Tl[row][c] = f2bf(v0 - bf2f(hb));
                hb = f2bf(v1); Th[row][16 + c] = hb; Tl[row][16 + c] = f2bf(v1 - bf2f(hb));
            }
        }
        __syncthreads();
        if (t < 128) {
            s16x8 hh = *reinterpret_cast<const s16x8*>(&Th[tile * 16 + c][q * 8]);
            s16x8 hl = *reinterpret_cast<const s16x8*>(&Tl[tile * 16 + c][q * 8]);
            f32x4 z0 = {0.f, 0.f, 0.f, 0.f}, z1 = {0.f, 0.f, 0.f, 0.f};
            z0 = MFMA_BF16(hh, fh[0], z0, 0, 0, 0);
            z0 = MFMA_BF16(hl, fh[0], z0, 0, 0, 0);
            z0 = MFMA_BF16(hh, fl[0], z0, 0, 0, 0);
            z1 = MFMA_BF16(hh, fh[1], z1, 0, 0, 0);
            z1 = MFMA_BF16(hl, fh[1], z1, 0, 0, 0);
            z1 = MFMA_BF16(hh, fl[1], z1, 0, 0, 0);
            float f1b0 = fc1b[c], f1b1 = fc1b[16 + c];
            float w20 = fc2W[c], w21 = fc2W[16 + c];
            float f2b = fc2b[0];
#pragma unroll
            for (int rr = 0; rr < 4; ++rr) {
                float zz0 = fmaxf(z0[rr] + f1b0, 0.f);
                float zz1 = fmaxf(z1[rr] + f1b1, 0.f);
                float v = fmaf(zz0, w20, zz1 * w21);
                v += __shfl_xor(v, 1);
                v += __shfl_xor(v, 2);
                v += __shfl_xor(v, 4);
                v += __shfl_xor(v, 8);
                int n = base + tile * 16 + q * 4 + rr;
                if (c == 0 && n < N) out[n] = v + f2b;
            }
        }
        __syncthreads();  // Sl/Th/Tl reuse barrier
    }
}

static inline size_t align256(size_t v) { return (v + 255) & ~(size_t)255; }

extern "C" void kernel_launch(void* const* d_in, const int* in_sizes, int n_in,
                              void* d_out, int out_size, void* d_ws, size_t ws_size,
                              hipStream_t stream) {
    const float* x = (const float*)d_in[0];
    const int* ei = (const int*)d_in[1];
    const float* ea = (const float*)d_in[2];
    const float* nn1W = (const float*)d_in[3];
    const float* nn1b = (const float*)d_in[4];
    const float* root1 = (const float*)d_in[5];
    const float* b1 = (const float*)d_in[6];
    const float* nn2W = (const float*)d_in[7];
    const float* nn2b = (const float*)d_in[8];
    const float* root2 = (const float*)d_in[9];
    const float* b2 = (const float*)d_in[10];
    const float* nn3W = (const float*)d_in[11];
    const float* nn3b = (const float*)d_in[12];
    const float* root3 = (const float*)d_in[13];
    const float* b3 = (const float*)d_in[14];
    const float* fc1W = (const float*)d_in[15];
    const float* fc1b = (const float*)d_in[16];
    const float* fc2W = (const float*)d_in[17];
    const float* fc2b = (const float*)d_in[18];

    const int N = in_sizes[0] / 2;   // 20000
    const int E = in_sizes[2] / 2;   // 150000
    const int* src = ei;
    const int* dst = ei + E;

    char* w = (char*)d_ws;
    int* cnt = (int*)w;     w += align256((size_t)N * 4);
    int4* edges = (int4*)w; w += align256((size_t)N * CAP * 16);
    float* h1 = (float*)w;  w += align256((size_t)N * 32 * 4);
    float* h2 = (float*)w;  w += align256((size_t)N * 32 * 4);

    float* out = (float*)d_out;

    zero_kernel<<<(N + 255) / 256, 256, 0, stream>>>(cnt, N);

    int sb = (E + 511) / 512;  // 2 edges per thread, 293 blocks (all CUs busy)
    scatter_kernel<<<sb, 256, 0, stream>>>(src, dst, ea, cnt, edges, E);

    int gb = (N + 7) / 8;  // 2500
    conv1_kernel<<<gb, 256, 0, stream>>>(x, cnt, edges, nn1W, nn1b, root1, b1, h1, N);
    fused2_kernel<<<512, 1024, 0, stream>>>(h1, cnt, edges, nn2W, nn2b, root2, b2,
                                            h2, N);
    fused3_kernel<<<512, 1024, 0, stream>>>(h2, cnt, edges, nn3W, nn3b, root3, b3,
                                            fc1W, fc1b, fc2W, fc2b, out, N);
}

// Round 22
// 65.319 us; speedup vs baseline: 1.0367x; 1.0367x over previous
//
#include <hip/hip_runtime.h>

// NNConv x3 + MLP head, 5 dispatches. BEST-KNOWN config (R20) + scatter spread.
// W_e = a0*A0 + a1*A1 + B (affine in 2 edge attrs) =>
//   aggr_n = [s0;s1;s2;s3] @ [A0;A1;B;R],  s0=sum a0*h_src, s1=sum a1*h_src,
//   s2=sum w*h_src (w=1), s3=h_self.
// Padded CSR (CAP=32), reg-clamped pads. Fused: 1024 thr / 32 nodes one-shot
// (625 blocks; R21 showed grid-stride persistence regresses via tail imbalance).
// Scatter: 293 blocks x 2 edges/thread (all CUs busy; same chain concurrency).
// Kernels: zero(cnt) | scatter | conv1 | fused2 | fused3+head.

#define CAP 32

typedef float f32x4 __attribute__((ext_vector_type(4)));
typedef short s16x8 __attribute__((ext_vector_type(8)));

__device__ __forceinline__ unsigned short f2bf(float x) {
    unsigned u = __float_as_uint(x);
    unsigned r = u + 0x7FFFu + ((u >> 16) & 1u);
    return (unsigned short)(r >> 16);
}
__device__ __forceinline__ float bf2f(unsigned short h) {
    return __uint_as_float(((unsigned)h) << 16);
}

__global__ __launch_bounds__(256) void zero_kernel(int* p, int n) {
    int i = blockIdx.x * 256 + threadIdx.x;
    if (i < n) p[i] = 0;
}

__global__ __launch_bounds__(256) void scatter_kernel(
    const int* __restrict__ src, const int* __restrict__ dst,
    const float* __restrict__ ea, int* __restrict__ cnt,
    int4* __restrict__ edges, int E) {
    int tid = blockIdx.x * 256 + threadIdx.x;
    int T = gridDim.x * 256;
#pragma unroll 2
    for (int k = 0; k < 2; ++k) {
        int e = tid + k * T;
        if (e < E) {
            int d = dst[e];
            int p = atomicAdd(&cnt[d], 1);
            if (p < CAP) {
                float2 a = ((const float2*)ea)[e];
                int4 ed;
                ed.x = __float_as_int(1.0f);
                ed.y = __float_as_int(a.x);
                ed.z = __float_as_int(a.y);
                ed.w = src[e] * 32;
                edges[((size_t)d << 5) + p] = ed;
            }
        }
    }
}

// conv1: in=2, out=32. 8 nodes/block (half-wave each). Rec-clamped pads;
// 8-wide batches via shfl broadcasts.
__global__ __launch_bounds__(256) void conv1_kernel(
    const float* __restrict__ x, const int* __restrict__ cnt,
    const int4* __restrict__ edges, const float* __restrict__ nnW,
    const float* __restrict__ nnb, const float* __restrict__ root,
    const float* __restrict__ bias, float* __restrict__ hout, int N) {
    int tid = threadIdx.x;
    int g = tid >> 5, lane = tid & 31;
    int n = blockIdx.x * 8 + g;
    if (n >= N) return;
    int deg = cnt[n];
    deg = (deg < CAP) ? deg : CAP;
    int deg8 = (deg + 7) & ~7;
    const int4* ep = &edges[(size_t)n << 5];
    int4 rec = {0, 0, 0, 0};
    if (lane < deg) rec = ep[lane];
    float p0 = 0, p1 = 0, q0 = 0, q1 = 0, r0 = 0, r1 = 0;
    for (int p = 0; p < deg8; p += 8) {
        float2 xv[8];
        float a0[8], a1[8], ww[8];
#pragma unroll
        for (int j = 0; j < 8; ++j) {
            int off = __shfl(rec.w, p + j, 32);
            a0[j] = __int_as_float(__shfl(rec.y, p + j, 32));
            a1[j] = __int_as_float(__shfl(rec.z, p + j, 32));
            ww[j] = __int_as_float(__shfl(rec.x, p + j, 32));
            xv[j] = ((const float2*)x)[off >> 5];
        }
#pragma unroll
        for (int j = 0; j < 8; ++j) {
            p0 = fmaf(a0[j], xv[j].x, p0);
            p1 = fmaf(a0[j], xv[j].y, p1);
            q0 = fmaf(a1[j], xv[j].x, q0);
            q1 = fmaf(a1[j], xv[j].y, q1);
            r0 = fmaf(ww[j], xv[j].x, r0);
            r1 = fmaf(ww[j], xv[j].y, r1);
        }
    }
    float acc = bias[lane];
    acc = fmaf(p0, nnW[lane * 2], acc);
    acc = fmaf(p1, nnW[(32 + lane) * 2], acc);
    acc = fmaf(q0, nnW[lane * 2 + 1], acc);
    acc = fmaf(q1, nnW[(32 + lane) * 2 + 1], acc);
    acc = fmaf(r0, nnb[lane], acc);
    acc = fmaf(r1, nnb[32 + lane], acc);
    float2 xn = ((const float2*)x)[n];
    acc = fmaf(xn.x, root[lane], acc);
    acc = fmaf(xn.y, root[32 + lane], acc);
    hout[n * 32 + lane] = fmaxf(acc, 0.f);
}

// Stage the 4x[32x32] weight stack transposed into LDS as bf16 hi/lo:
// Whi[kc][o][k]. kc: 0=A0, 1=A1, 2=B(nnb), 3=R(root).
template <int BS>
__device__ __forceinline__ void stage_weights(
    const float* __restrict__ nnW, const float* __restrict__ nnb,
    const float* __restrict__ root, unsigned short (*Whi)[32][32],
    unsigned short (*Wlo)[32][32], int t) {
    for (int idx = t; idx < 4096; idx += BS) {
        int kc = idx >> 10, r = idx & 1023, k = r >> 5, o = r & 31;
        float v = (kc == 0)   ? nnW[(k * 32 + o) * 2]
                  : (kc == 1) ? nnW[(k * 32 + o) * 2 + 1]
                  : (kc == 2) ? nnb[k * 32 + o]
                              : root[k * 32 + o];
        unsigned short hb = f2bf(v);
        Whi[kc][o][k] = hb;
        Wlo[kc][o][k] = f2bf(v - bf2f(hb));
    }
}

#define MFMA_BF16 __builtin_amdgcn_mfma_f32_16x16x32_bf16

// Gather: 32 half-wave groups (1024-thr block), ONE node each, single pass.
// Rec-clamped pads; 8-wide batches; 8 independent h-row loads in flight.
__device__ __forceinline__ void gather_to_lds(
    const float* __restrict__ h, const int* __restrict__ cnt,
    const int4* __restrict__ edges, float (*Sl)[132], int base, int t, int N) {
    int g = t >> 5, lane = t & 31;  // g in [0,32)
    int n = base + g;
    float s0 = 0, s1 = 0, s2 = 0, s3 = 0;
    if (n < N) {
        int deg = cnt[n];
        deg = (deg < CAP) ? deg : CAP;
        int deg8 = (deg + 7) & ~7;
        const int4* ep = &edges[(size_t)n << 5];
        int4 rec = {0, 0, 0, 0};
        if (lane < deg) rec = ep[lane];
        s3 = h[n * 32 + lane];
        for (int p = 0; p < deg8; p += 8) {
            float hv[8], a0[8], a1[8], ww[8];
#pragma unroll
            for (int j = 0; j < 8; ++j) {
                int off = __shfl(rec.w, p + j, 32);
                a0[j] = __int_as_float(__shfl(rec.y, p + j, 32));
                a1[j] = __int_as_float(__shfl(rec.z, p + j, 32));
                ww[j] = __int_as_float(__shfl(rec.x, p + j, 32));
                hv[j] = h[off + lane];
            }
#pragma unroll
            for (int j = 0; j < 8; ++j) {
                s0 = fmaf(a0[j], hv[j], s0);
                s1 = fmaf(a1[j], hv[j], s1);
                s2 = fmaf(ww[j], hv[j], s2);
            }
        }
    }
    Sl[g][lane] = s0;
    Sl[g][32 + lane] = s1;
    Sl[g][64 + lane] = s2;
    Sl[g][96 + lane] = s3;
}

// MFMA tile: acc = S-tile @ [A0;A1;B;R]. A-frag row=c, k=q*8+e;
// C/D row=q*4+rr, col=c (m89-verified, R8-validated end-to-end).
__device__ __forceinline__ void tile_mfma(
    const float (*Sl)[132], const unsigned short (*Whi)[32][32],
    const unsigned short (*Wlo)[32][32], int q, int c, f32x4* acc0, f32x4* acc1) {
#pragma unroll
    for (int kc = 0; kc < 4; ++kc) {
        const float* sp = &Sl[c][kc * 32 + q * 8];
        s16x8 ah, al;
#pragma unroll
        for (int e = 0; e < 8; ++e) {
            float v = sp[e];
            unsigned short hb = f2bf(v);
            ah[e] = (short)hb;
            al[e] = (short)f2bf(v - bf2f(hb));
        }
        s16x8 bh0 = *reinterpret_cast<const s16x8*>(&Whi[kc][c][q * 8]);
        s16x8 bl0 = *reinterpret_cast<const s16x8*>(&Wlo[kc][c][q * 8]);
        s16x8 bh1 = *reinterpret_cast<const s16x8*>(&Whi[kc][16 + c][q * 8]);
        s16x8 bl1 = *reinterpret_cast<const s16x8*>(&Wlo[kc][16 + c][q * 8]);
        *acc0 = MFMA_BF16(ah, bh0, *acc0, 0, 0, 0);
        *acc0 = MFMA_BF16(al, bh0, *acc0, 0, 0, 0);
        *acc0 = MFMA_BF16(ah, bl0, *acc0, 0, 0, 0);
        *acc1 = MFMA_BF16(ah, bh1, *acc1, 0, 0, 0);
        *acc1 = MFMA_BF16(al, bh1, *acc1, 0, 0, 0);
        *acc1 = MFMA_BF16(ah, bl1, *acc1, 0, 0, 0);
    }
}

// fused2: gather(h1) -> LDS -> MFMA -> h2. 32 nodes/block, 1024 thr, 2 MFMA waves.
__global__ __launch_bounds__(1024) void fused2_kernel(
    const float* __restrict__ h, const int* __restrict__ cnt,
    const int4* __restrict__ edges, const float* __restrict__ nnW,
    const float* __restrict__ nnb, const float* __restrict__ root,
    const float* __restrict__ bias, float* __restrict__ hout, int N) {
    __shared__ unsigned short Whi[4][32][32], Wlo[4][32][32];
    __shared__ float Sl[32][132];
    int t = threadIdx.x;
    int base = blockIdx.x * 32;
    stage_weights<1024>(nnW, nnb, root, Whi, Wlo, t);
    gather_to_lds(h, cnt, edges, Sl, base, t, N);
    __syncthreads();
    if (t < 128) {
        int tile = t >> 6;          // 0 or 1: rows tile*16 .. tile*16+15
        int l = t & 63;
        int q = l >> 4, c = l & 15;
        f32x4 acc0 = {0.f, 0.f, 0.f, 0.f}, acc1 = {0.f, 0.f, 0.f, 0.f};
        tile_mfma(&Sl[tile * 16], Whi, Wlo, q, c, &acc0, &acc1);
        float bb0 = bias[c], bb1 = bias[16 + c];
#pragma unroll
        for (int rr = 0; rr < 4; ++rr) {
            int n = base + tile * 16 + q * 4 + rr;
            if (n < N) {
                hout[(size_t)n * 32 + c] = fmaxf(acc0[rr] + bb0, 0.f);
                hout[(size_t)n * 32 + 16 + c] = fmaxf(acc1[rr] + bb1, 0.f);
            }
        }
    }
}

// fused3: gather(h2) -> LDS -> MFMA -> h3 -> head fc1(relu)+fc2 -> out[N].
__global__ __launch_bounds__(1024) void fused3_kernel(
    const float* __restrict__ h, const int* __restrict__ cnt,
    const int4* __restrict__ edges, const float* __restrict__ nnW,
    const float* __restrict__ nnb, const float* __restrict__ root,
    const float* __restrict__ bias, const float* __restrict__ fc1W,
    const float* __restrict__ fc1b, const float* __restrict__ fc2W,
    const float* __restrict__ fc2b, float* __restrict__ out, int N) {
    __shared__ unsigned short Whi[4][32][32], Wlo[4][32][32];
    __shared__ float Sl[32][132];
    __shared__ unsigned short Th[32][32], Tl[32][32];
    int t = threadIdx.x;
    int base = blockIdx.x * 32;
    stage_weights<1024>(nnW, nnb, root, Whi, Wlo, t);
    gather_to_lds(h, cnt, edges, Sl, base, t, N);
    __syncthreads();
    int tile = t >> 6;
    int l = t & 63;
    int q = l >> 4, c = l & 15;
    if (t < 128) {
        f32x4 acc0 = {0.f, 0.f, 0.f, 0.f}, acc1 = {0.f, 0.f, 0.f, 0.f};
        tile_mfma(&Sl[tile * 16], Whi, Wlo, q, c, &acc0, &acc1);
        float bb0 = bias[c], bb1 = bias[16 + c];
#pragma unroll
        for (int rr = 0; rr < 4; ++rr) {
            int row = tile * 16 + q * 4 + rr;
            float v0 = fmaxf(acc0[rr] + bb0, 0.f);
            float v1 = fmaxf(acc1[rr] + bb1, 0.f);
            unsigned short hb;
            hb = f2bf(v0); Th[row][c] = hb;      Tl[row][c] = f2bf(v0 - bf2f(hb));
            hb = f2bf(v1); Th[row][16 + c] = hb; Tl[row][16 + c] = f2bf(v1 - bf2f(hb));
        }
    }
    __syncthreads();
    if (t < 128) {
        // fc1 B-frags: B[k=q*8+e][col=nc*16+c] = fc1W[(nc*16+c)*32+k]
        s16x8 fh[2], fl[2];
#pragma unroll
        for (int nc = 0; nc < 2; ++nc)
#pragma unroll
            for (int e = 0; e < 8; ++e) {
                float v = fc1W[(nc * 16 + c) * 32 + q * 8 + e];
                unsigned short hb = f2bf(v);
                fh[nc][e] = (short)hb;
                fl[nc][e] = (short)f2bf(v - bf2f(hb));
            }
        s16x8 hh = *reinterpret_cast<const s16x8*>(&Th[tile * 16 + c][q * 8]);
        s16x8 hl = *reinterpret_cast<const s16x8*>(&Tl[tile * 16 + c][q * 8]);
        f32x4 z0 = {0.f, 0.f, 0.f, 0.f}, z1 = {0.f, 0.f, 0.f, 0.f};
        z0 = MFMA_BF16(hh, fh[0], z0, 0, 0, 0);
        z0 = MFMA_BF16(hl, fh[0], z0, 0, 0, 0);
        z0 = MFMA_BF16(hh, fl[0], z0, 0, 0, 0);
        z1 = MFMA_BF16(hh, fh[1], z1, 0, 0, 0);
        z1 = MFMA_BF16(hl, fh[1], z1, 0, 0, 0);
        z1 = MFMA_BF16(hh, fl[1], z1, 0, 0, 0);
        float f1b0 = fc1b[c], f1b1 = fc1b[16 + c];
        float w20 = fc2W[c], w21 = fc2W[16 + c];
        float f2b = fc2b[0];
#pragma unroll
        for (int rr = 0; rr < 4; ++rr) {
            float zz0 = fmaxf(z0[rr] + f1b0, 0.f);
            float zz1 = fmaxf(z1[rr] + f1b1, 0.f);
            float v = fmaf(zz0, w20, zz1 * w21);
            v += __shfl_xor(v, 1);
            v += __shfl_xor(v, 2);
            v += __shfl_xor(v, 4);
            v += __shfl_xor(v, 8);
            int n = base + tile * 16 + q * 4 + rr;
            if (c == 0 && n < N) out[n] = v + f2b;
        }
    }
}

static inline size_t align256(size_t v) { return (v + 255) & ~(size_t)255; }

extern "C" void kernel_launch(void* const* d_in, const int* in_sizes, int n_in,
                              void* d_out, int out_size, void* d_ws, size_t ws_size,
                              hipStream_t stream) {
    const float* x = (const float*)d_in[0];
    const int* ei = (const int*)d_in[1];
    const float* ea = (const float*)d_in[2];
    const float* nn1W = (const float*)d_in[3];
    const float* nn1b = (const float*)d_in[4];
    const float* root1 = (const float*)d_in[5];
    const float* b1 = (const float*)d_in[6];
    const float* nn2W = (const float*)d_in[7];
    const float* nn2b = (const float*)d_in[8];
    const float* root2 = (const float*)d_in[9];
    const float* b2 = (const float*)d_in[10];
    const float* nn3W = (const float*)d_in[11];
    const float* nn3b = (const float*)d_in[12];
    const float* root3 = (const float*)d_in[13];
    const float* b3 = (const float*)d_in[14];
    const float* fc1W = (const float*)d_in[15];
    const float* fc1b = (const float*)d_in[16];
    const float* fc2W = (const float*)d_in[17];
    const float* fc2b = (const float*)d_in[18];

    const int N = in_sizes[0] / 2;   // 20000
    const int E = in_sizes[2] / 2;   // 150000
    const int* src = ei;
    const int* dst = ei + E;

    char* w = (char*)d_ws;
    int* cnt = (int*)w;     w += align256((size_t)N * 4);
    int4* edges = (int4*)w; w += align256((size_t)N * CAP * 16);
    float* h1 = (float*)w;  w += align256((size_t)N * 32 * 4);
    float* h2 = (float*)w;  w += align256((size_t)N * 32 * 4);

    float* out = (float*)d_out;

    zero_kernel<<<(N + 255) / 256, 256, 0, stream>>>(cnt, N);

    int sb = (E + 511) / 512;  // 2 edges per thread, 293 blocks (all CUs busy)
    scatter_kernel<<<sb, 256, 0, stream>>>(src, dst, ea, cnt, edges, E);

    int gb = (N + 7) / 8;     // 2500
    int fb = (N + 31) / 32;   // 625
    conv1_kernel<<<gb, 256, 0, stream>>>(x, cnt, edges, nn1W, nn1b, root1, b1, h1, N);
    fused2_kernel<<<fb, 1024, 0, stream>>>(h1, cnt, edges, nn2W, nn2b, root2, b2, h2, N);
    fused3_kernel<<<fb, 1024, 0, stream>>>(h2, cnt, edges, nn3W, nn3b, root3, b3,
                                           fc1W, fc1b, fc2W, fc2b, out, N);
}